// Round 2
// baseline (2790.995 us; speedup 1.0000x reference)
//
#include <hip/hip_runtime.h>

typedef unsigned short ushort_t;

__device__ __forceinline__ float bf2f(ushort_t u) {
    union { unsigned int i; float f; } v; v.i = ((unsigned int)u) << 16; return v.f;
}
__device__ __forceinline__ ushort_t f2b(float f) {
    union { float f; unsigned int i; } v; v.f = f;
    unsigned int x = v.i;
    unsigned int r = (x + 0x7fffu + ((x >> 16) & 1u)) >> 16;
    return (ushort_t)r;
}
__device__ __forceinline__ void unpack8(float* dst, uint4 u) {
    unsigned int w[4] = {u.x, u.y, u.z, u.w};
#pragma unroll
    for (int i = 0; i < 4; ++i) {
        union { unsigned int i; float f; } lo, hi;
        lo.i = (w[i] & 0xffffu) << 16;
        hi.i = w[i] & 0xffff0000u;
        dst[2 * i]     = lo.f;
        dst[2 * i + 1] = hi.f;
    }
}

// C[n,o] = sum_d A[n,d]*W[o,d] + bias[o]
// W: [768][768] fp32 row-major (torch Linear weight), bias fp32.
// MODE 0: A = fp32 [8192][768] (hidden_states); C = bf16, stored to
//         [B=4][H=12][L=2048][HD=64] (b=n>>11, l=n&2047, h=o>>6, hd=o&63)
// MODE 1: A = bf16 [8192][768] (attention out);  C = fp32 row-major [n][o]
template<int MODE>
__global__ __launch_bounds__(256)
void gemm_tn(const void* __restrict__ A_, const float* __restrict__ W,
             const float* __restrict__ bias, void* __restrict__ C_)
{
    __shared__ float As[64][65];
    __shared__ float Ws[64][65];
    const int t  = threadIdx.x;
    const int tx = t & 15, ty = t >> 4;
    const int n0 = blockIdx.x << 6;
    const int o0 = blockIdx.y << 6;
    const int lr = t >> 2, lc = (t & 3) << 4;

    float acc[4][4] = {};

    const float* pw = W + (size_t)(o0 + lr) * 768 + lc;

    for (int d0 = 0; d0 < 768; d0 += 64) {
        float a[16], w[16];
        if (MODE == 0) {
            const float* pa = (const float*)A_ + (size_t)(n0 + lr) * 768 + d0 + lc;
#pragma unroll
            for (int i = 0; i < 4; ++i) {
                const float4 v = ((const float4*)pa)[i];
                a[4 * i] = v.x; a[4 * i + 1] = v.y; a[4 * i + 2] = v.z; a[4 * i + 3] = v.w;
            }
        } else {
            const ushort_t* pa = (const ushort_t*)A_ + (size_t)(n0 + lr) * 768 + d0 + lc;
            uint4 x0 = *(const uint4*)pa;
            uint4 x1 = *(const uint4*)(pa + 8);
            unpack8(a, x0);
            unpack8(a + 8, x1);
        }
        {
            const float* p = pw + d0;
#pragma unroll
            for (int i = 0; i < 4; ++i) {
                const float4 v = ((const float4*)p)[i];
                w[4 * i] = v.x; w[4 * i + 1] = v.y; w[4 * i + 2] = v.z; w[4 * i + 3] = v.w;
            }
        }
        __syncthreads();   // guard previous iteration's LDS reads
#pragma unroll
        for (int i = 0; i < 16; ++i) { As[lr][lc + i] = a[i]; Ws[lr][lc + i] = w[i]; }
        __syncthreads();
#pragma unroll 4
        for (int d = 0; d < 64; ++d) {
            float ar[4], wr[4];
#pragma unroll
            for (int i = 0; i < 4; ++i) ar[i] = As[(ty << 2) + i][d];
#pragma unroll
            for (int j = 0; j < 4; ++j) wr[j] = Ws[(tx << 2) + j][d];
#pragma unroll
            for (int i = 0; i < 4; ++i)
#pragma unroll
                for (int j = 0; j < 4; ++j) acc[i][j] = fmaf(ar[i], wr[j], acc[i][j]);
        }
    }

#pragma unroll
    for (int i = 0; i < 4; ++i) {
        const int n = n0 + (ty << 2) + i;
#pragma unroll
        for (int j = 0; j < 4; ++j) {
            const int o = o0 + (tx << 2) + j;
            const float v = acc[i][j] + bias[o];
            if (MODE == 0) {
                const size_t dst = ((size_t)((n >> 11) * 12 + (o >> 6)) << 17)
                                 + ((size_t)(n & 2047) << 6) + (o & 63);
                ((ushort_t*)C_)[dst] = f2b(v);
            } else {
                ((float*)C_)[(size_t)n * 768 + o] = v;
            }
        }
    }
}

// Flash-style causal attention.
// Q,K,V: [48][2048][64] bf16 (bh-major). AO: [4][2048][768] bf16 (b,l, h*64+hd).
// Block = 256 threads, one block per (bh, 64-query tile). Key chunks of 64.
__global__ __launch_bounds__(256)
void attn_fwd(const ushort_t* __restrict__ Q, const ushort_t* __restrict__ K,
              const ushort_t* __restrict__ V, ushort_t* __restrict__ AO)
{
    __shared__ float Qs[64][68];
    __shared__ float Ks[64][68];
    __shared__ float Vs[64][68];
    __shared__ float mrow[64];
    __shared__ float lrow[64];

    const int t  = threadIdx.x;
    const int bh = blockIdx.y;            // b*12 + h
    const int qt = 31 - blockIdx.x;       // heavy tiles first
    const int q0 = qt << 6;
    const int lr = t >> 2, lc = (t & 3) << 4;
    const int oq = t >> 2;                // owned query row (0..63)
    const int g  = t & 3;                 // lane within row-quad
    const int od = g << 4;                // owned 16-wide d-block / k-block

    const size_t base = (size_t)bh << 17; // bh * 2048 * 64

    {   // load Q tile (fp32 in LDS)
        const ushort_t* p = Q + base + ((size_t)(q0 + lr) << 6) + lc;
        uint4 x0 = *(const uint4*)p;
        uint4 x1 = *(const uint4*)(p + 8);
        unpack8(&Qs[lr][lc], x0);
        unpack8(&Qs[lr][lc + 8], x1);
    }
    if (g == 0) { mrow[oq] = -3.0e38f; lrow[oq] = 0.f; }
    float o_acc[16];
#pragma unroll
    for (int i = 0; i < 16; ++i) o_acc[i] = 0.f;
    __syncthreads();

    const int qglob = q0 + oq;
    for (int c = 0; c <= qt; ++c) {
        const int k0 = c << 6;
        const ushort_t* pk = K + base + ((size_t)(k0 + lr) << 6) + lc;
        const ushort_t* pv = V + base + ((size_t)(k0 + lr) << 6) + lc;
        uint4 ka = *(const uint4*)pk;
        uint4 kb = *(const uint4*)(pk + 8);
        uint4 va = *(const uint4*)pv;
        uint4 vb = *(const uint4*)(pv + 8);
        __syncthreads();   // previous chunk's Vs reads complete
        unpack8(&Ks[lr][lc], ka); unpack8(&Ks[lr][lc + 8], kb);
        unpack8(&Vs[lr][lc], va); unpack8(&Vs[lr][lc + 8], vb);
        __syncthreads();

        // S for keys [k0+od, k0+od+16) of row oq
        float p_reg[16];
#pragma unroll
        for (int kk = 0; kk < 16; ++kk) p_reg[kk] = 0.f;
#pragma unroll 4
        for (int d = 0; d < 64; d += 4) {
            const float4 q4 = *(const float4*)&Qs[oq][d];
#pragma unroll
            for (int kk = 0; kk < 16; ++kk) {
                const float4 k4 = *(const float4*)&Ks[od + kk][d];
                p_reg[kk] += q4.x * k4.x + q4.y * k4.y + q4.z * k4.z + q4.w * k4.w;
            }
        }
        // scale, causal mask, row max (across the 4 lanes of this row)
        float mloc = -3.0e38f;
#pragma unroll
        for (int kk = 0; kk < 16; ++kk) {
            float s = p_reg[kk] * 0.125f;
            if (k0 + od + kk > qglob) s = -3.0e38f;
            p_reg[kk] = s;
            mloc = fmaxf(mloc, s);
        }
        mloc = fmaxf(mloc, __shfl_xor(mloc, 1));
        mloc = fmaxf(mloc, __shfl_xor(mloc, 2));
        const float m_old = mrow[oq];
        const float m_new = fmaxf(m_old, mloc);
        const float alpha = __expf(m_old - m_new);
        float lsum = 0.f;
#pragma unroll
        for (int kk = 0; kk < 16; ++kk) {
            const float p = __expf(p_reg[kk] - m_new);
            p_reg[kk] = p;
            lsum += p;
        }
        lsum += __shfl_xor(lsum, 1);
        lsum += __shfl_xor(lsum, 2);
        if (g == 0) { mrow[oq] = m_new; lrow[oq] = lrow[oq] * alpha + lsum; }

        // O update: o_acc covers d in [od, od+16) of row oq
#pragma unroll
        for (int i = 0; i < 16; ++i) o_acc[i] *= alpha;
        const int srcbase = t & ~3;
        for (int kg = 0; kg < 4; ++kg) {
#pragma unroll
            for (int kk = 0; kk < 16; ++kk) {
                const float p = __shfl(p_reg[kk], srcbase + kg);
                const int k = (kg << 4) + kk;
                const float4* vp = (const float4*)&Vs[k][od];
#pragma unroll
                for (int i = 0; i < 4; ++i) {
                    const float4 v4 = vp[i];
                    o_acc[(i << 2) + 0] += p * v4.x;
                    o_acc[(i << 2) + 1] += p * v4.y;
                    o_acc[(i << 2) + 2] += p * v4.z;
                    o_acc[(i << 2) + 3] += p * v4.w;
                }
            }
        }
    }
    __syncthreads();
    const float linv = 1.f / lrow[oq];
    const int b = bh / 12, h = bh % 12;
    const size_t dst = ((size_t)(b * 2048 + q0 + oq)) * 768 + h * 64 + od;
#pragma unroll
    for (int i = 0; i < 16; ++i) AO[dst + i] = f2b(o_acc[i] * linv);
}

extern "C" void kernel_launch(void* const* d_in, const int* in_sizes, int n_in,
                              void* d_out, int out_size, void* d_ws, size_t ws_size,
                              hipStream_t stream) {
    const float* hs = (const float*)d_in[0];
    const float* wq = (const float*)d_in[1];
    const float* bq = (const float*)d_in[2];
    const float* wk = (const float*)d_in[3];
    const float* bk = (const float*)d_in[4];
    const float* wv = (const float*)d_in[5];
    const float* bv = (const float*)d_in[6];
    const float* wo = (const float*)d_in[7];
    const float* bo = (const float*)d_in[8];
    float* out = (float*)d_out;

    const size_t NB = (size_t)8192 * 768;     // elements per [B*L, DM] tensor
    ushort_t* Qb = (ushort_t*)d_ws;
    ushort_t* Kb = Qb + NB;
    ushort_t* Vb = Kb + NB;
    ushort_t* AO = Vb + NB;

    dim3 blk(256);
    gemm_tn<0><<<dim3(128, 12), blk, 0, stream>>>(hs, wq, bq, Qb);
    gemm_tn<0><<<dim3(128, 12), blk, 0, stream>>>(hs, wk, bk, Kb);
    gemm_tn<0><<<dim3(128, 12), blk, 0, stream>>>(hs, wv, bv, Vb);
    attn_fwd<<<dim3(32, 48), blk, 0, stream>>>(Qb, Kb, Vb, AO);
    gemm_tn<1><<<dim3(128, 12), blk, 0, stream>>>(AO, wo, bo, out);
}

// Round 3
// 1035.070 us; speedup vs baseline: 2.6964x; 2.6964x over previous
//
#include <hip/hip_runtime.h>

typedef unsigned short ushort_t;
typedef __attribute__((ext_vector_type(8))) short short8;
typedef __attribute__((ext_vector_type(4))) float f32x4;

__device__ __forceinline__ float bf2f(ushort_t u) {
    union { unsigned int i; float f; } v; v.i = ((unsigned int)u) << 16; return v.f;
}
__device__ __forceinline__ ushort_t f2b(float f) {
    union { float f; unsigned int i; } v; v.f = f;
    unsigned int x = v.i;
    unsigned int r = (x + 0x7fffu + ((x >> 16) & 1u)) >> 16;
    return (ushort_t)r;
}
__device__ __forceinline__ void unpack8(float* dst, uint4 u) {
    unsigned int w[4] = {u.x, u.y, u.z, u.w};
#pragma unroll
    for (int i = 0; i < 4; ++i) {
        union { unsigned int i; float f; } lo, hi;
        lo.i = (w[i] & 0xffffu) << 16;
        hi.i = w[i] & 0xffff0000u;
        dst[2 * i]     = lo.f;
        dst[2 * i + 1] = hi.f;
    }
}

// ---------------- projection GEMMs (unchanged from round 2, known-good) ----
// C[n,o] = sum_d A[n,d]*W[o,d] + bias[o]
// MODE 0: A = fp32 hidden_states; C = bf16 [B=4][H=12][L=2048][HD=64]
// MODE 1: A = bf16 attention out;  C = fp32 row-major [n][o]
template<int MODE>
__global__ __launch_bounds__(256)
void gemm_tn(const void* __restrict__ A_, const float* __restrict__ W,
             const float* __restrict__ bias, void* __restrict__ C_)
{
    __shared__ float As[64][65];
    __shared__ float Ws[64][65];
    const int t  = threadIdx.x;
    const int tx = t & 15, ty = t >> 4;
    const int n0 = blockIdx.x << 6;
    const int o0 = blockIdx.y << 6;
    const int lr = t >> 2, lc = (t & 3) << 4;

    float acc[4][4] = {};

    const float* pw = W + (size_t)(o0 + lr) * 768 + lc;

    for (int d0 = 0; d0 < 768; d0 += 64) {
        float a[16], w[16];
        if (MODE == 0) {
            const float* pa = (const float*)A_ + (size_t)(n0 + lr) * 768 + d0 + lc;
#pragma unroll
            for (int i = 0; i < 4; ++i) {
                const float4 v = ((const float4*)pa)[i];
                a[4 * i] = v.x; a[4 * i + 1] = v.y; a[4 * i + 2] = v.z; a[4 * i + 3] = v.w;
            }
        } else {
            const ushort_t* pa = (const ushort_t*)A_ + (size_t)(n0 + lr) * 768 + d0 + lc;
            uint4 x0 = *(const uint4*)pa;
            uint4 x1 = *(const uint4*)(pa + 8);
            unpack8(a, x0);
            unpack8(a + 8, x1);
        }
        {
            const float* p = pw + d0;
#pragma unroll
            for (int i = 0; i < 4; ++i) {
                const float4 v = ((const float4*)p)[i];
                w[4 * i] = v.x; w[4 * i + 1] = v.y; w[4 * i + 2] = v.z; w[4 * i + 3] = v.w;
            }
        }
        __syncthreads();
#pragma unroll
        for (int i = 0; i < 16; ++i) { As[lr][lc + i] = a[i]; Ws[lr][lc + i] = w[i]; }
        __syncthreads();
#pragma unroll 4
        for (int d = 0; d < 64; ++d) {
            float ar[4], wr[4];
#pragma unroll
            for (int i = 0; i < 4; ++i) ar[i] = As[(ty << 2) + i][d];
#pragma unroll
            for (int j = 0; j < 4; ++j) wr[j] = Ws[(tx << 2) + j][d];
#pragma unroll
            for (int i = 0; i < 4; ++i)
#pragma unroll
                for (int j = 0; j < 4; ++j) acc[i][j] = fmaf(ar[i], wr[j], acc[i][j]);
        }
    }

#pragma unroll
    for (int i = 0; i < 4; ++i) {
        const int n = n0 + (ty << 2) + i;
#pragma unroll
        for (int j = 0; j < 4; ++j) {
            const int o = o0 + (tx << 2) + j;
            const float v = acc[i][j] + bias[o];
            if (MODE == 0) {
                const size_t dst = ((size_t)((n >> 11) * 12 + (o >> 6)) << 17)
                                 + ((size_t)(n & 2047) << 6) + (o & 63);
                ((ushort_t*)C_)[dst] = f2b(v);
            } else {
                ((float*)C_)[(size_t)n * 768 + o] = v;
            }
        }
    }
}

// ---------------- MFMA flash attention -----------------------------------
// Q,K,V: [48][2048][64] bf16 (bh-major). AO: [4][2048][768] bf16.
// Block = 256 threads (4 waves). Wave w owns 16 query rows [q0+16w, q0+16w+16).
// Key chunks of 64. mfma_f32_16x16x32_bf16:
//   A-frag: m = lane&15, k = 8*(lane>>4)+j  (8 contiguous bf16 along k)
//   B-frag: n = lane&15, k = 8*(lane>>4)+j
//   C/D:    col = lane&15, row = 4*(lane>>4)+reg   [verified m89]
#define VT_STRIDE 72   // ushorts; multiple of 8 keeps 16B-aligned b128 reads

__global__ __launch_bounds__(256)
void attn_mfma(const ushort_t* __restrict__ Q, const ushort_t* __restrict__ K,
               const ushort_t* __restrict__ V, ushort_t* __restrict__ AO)
{
    __shared__ ushort_t Vt[64 * VT_STRIDE];        // V transposed: Vt[d][key]
    __shared__ ushort_t Ps[4][16 * VT_STRIDE];     // per-wave P tile [q][key]

    const int t    = threadIdx.x;
    const int lane = t & 63;
    const int w    = t >> 6;
    const int bh   = blockIdx.y;
    const int qt   = 31 - (int)blockIdx.x;         // heavy tiles first
    const int q0   = qt << 6;
    const size_t base = (size_t)bh << 17;          // bh * 2048 * 64

    const int col = lane & 15;                     // m/n index within tile
    const int kg  = lane >> 4;                     // k-group (0..3)

    // Q A-fragments for this wave's 16 rows (load once, from global)
    short8 aq0, aq1;
    {
        const ushort_t* pq = Q + base + (size_t)(q0 + 16 * w + col) * 64 + kg * 8;
        aq0 = *(const short8*)(pq);
        aq1 = *(const short8*)(pq + 32);
    }

    float m_st[4], l_st[4];
#pragma unroll
    for (int r = 0; r < 4; ++r) { m_st[r] = -3.0e38f; l_st[r] = 0.f; }
    f32x4 o_acc[4];
#pragma unroll
    for (int vt = 0; vt < 4; ++vt) o_acc[vt] = (f32x4){0.f, 0.f, 0.f, 0.f};

    // V staging coords: key = lane, d-group = w (conflict-free Vt writes)
    const int vkey = lane, vdg = w;

    for (int c = 0; c <= qt; ++c) {
        const int k0 = c << 6;

        // K B-fragments straight from global (k-contiguous 16B reads)
        short8 bk[4][2];
#pragma unroll
        for (int kt = 0; kt < 4; ++kt) {
            const ushort_t* pk = K + base + (size_t)(k0 + kt * 16 + col) * 64 + kg * 8;
            bk[kt][0] = *(const short8*)(pk);
            bk[kt][1] = *(const short8*)(pk + 32);
        }
        // V chunk loads (before the barrier so VMEM overlaps the wait)
        const ushort_t* pv = V + base + (size_t)(k0 + vkey) * 64 + vdg * 16;
        const uint4 v0 = *(const uint4*)pv;
        const uint4 v1 = *(const uint4*)(pv + 8);

        __syncthreads();   // previous chunk's Vt reads complete
        {
            ushort_t tmp[16];
            *(uint4*)tmp = v0; *(uint4*)(tmp + 8) = v1;
#pragma unroll
            for (int i = 0; i < 16; ++i)
                Vt[(vdg * 16 + i) * VT_STRIDE + vkey] = tmp[i];
        }
        __syncthreads();   // Vt ready

        // S = Q K^T (scaled)
        f32x4 s[4];
#pragma unroll
        for (int kt = 0; kt < 4; ++kt) {
            f32x4 acc = (f32x4){0.f, 0.f, 0.f, 0.f};
            acc = __builtin_amdgcn_mfma_f32_16x16x32_bf16(aq0, bk[kt][0], acc, 0, 0, 0);
            acc = __builtin_amdgcn_mfma_f32_16x16x32_bf16(aq1, bk[kt][1], acc, 0, 0, 0);
            s[kt] = acc;
        }
        const int qrow_base = q0 + 16 * w + 4 * kg;   // + reg = this lane's rows
        if (c == qt) {
#pragma unroll
            for (int kt = 0; kt < 4; ++kt)
#pragma unroll
                for (int r = 0; r < 4; ++r) {
                    const int key = k0 + kt * 16 + col;
                    s[kt][r] = (key > qrow_base + r) ? -3.0e38f : s[kt][r] * 0.125f;
                }
        } else {
#pragma unroll
            for (int kt = 0; kt < 4; ++kt)
#pragma unroll
                for (int r = 0; r < 4; ++r) s[kt][r] *= 0.125f;
        }

        // online softmax per row (row-reduce = xor-shuffle over the 16 cols)
        float alpha[4];
#pragma unroll
        for (int r = 0; r < 4; ++r) {
            float mx = fmaxf(fmaxf(s[0][r], s[1][r]), fmaxf(s[2][r], s[3][r]));
            mx = fmaxf(mx, __shfl_xor(mx, 1));
            mx = fmaxf(mx, __shfl_xor(mx, 2));
            mx = fmaxf(mx, __shfl_xor(mx, 4));
            mx = fmaxf(mx, __shfl_xor(mx, 8));
            const float mn = fmaxf(m_st[r], mx);
            alpha[r] = __expf(m_st[r] - mn);
            m_st[r] = mn;
            float ls = 0.f;
#pragma unroll
            for (int kt = 0; kt < 4; ++kt) {
                const float p = __expf(s[kt][r] - mn);
                s[kt][r] = p;
                ls += p;
            }
            ls += __shfl_xor(ls, 1);
            ls += __shfl_xor(ls, 2);
            ls += __shfl_xor(ls, 4);
            ls += __shfl_xor(ls, 8);
            l_st[r] = l_st[r] * alpha[r] + ls;
        }

        // P: C-layout -> LDS -> A-layout (per-wave region, no barrier needed)
        ushort_t* ps = Ps[w];
#pragma unroll
        for (int kt = 0; kt < 4; ++kt)
#pragma unroll
            for (int r = 0; r < 4; ++r)
                ps[(4 * kg + r) * VT_STRIDE + kt * 16 + col] = f2b(s[kt][r]);
        short8 pa0, pa1;
        {
            const ushort_t* pp = ps + (size_t)col * VT_STRIDE + kg * 8;
            pa0 = *(const short8*)pp;
            pa1 = *(const short8*)(pp + 32);
        }

        // O = O*alpha + P V
#pragma unroll
        for (int vt = 0; vt < 4; ++vt) {
            f32x4 o = o_acc[vt];
#pragma unroll
            for (int r = 0; r < 4; ++r) o[r] *= alpha[r];
            const ushort_t* pvt = Vt + (vt * 16 + col) * VT_STRIDE + kg * 8;
            const short8 bv0 = *(const short8*)pvt;
            const short8 bv1 = *(const short8*)(pvt + 32);
            o = __builtin_amdgcn_mfma_f32_16x16x32_bf16(pa0, bv0, o, 0, 0, 0);
            o = __builtin_amdgcn_mfma_f32_16x16x32_bf16(pa1, bv1, o, 0, 0, 0);
            o_acc[vt] = o;
        }
    }

    // epilogue: normalize, store to AO[b][l][h*64+d]
    float linv[4];
#pragma unroll
    for (int r = 0; r < 4; ++r) linv[r] = 1.f / l_st[r];
    const int b = bh / 12, h = bh % 12;
#pragma unroll
    for (int vt = 0; vt < 4; ++vt)
#pragma unroll
        for (int r = 0; r < 4; ++r) {
            const int q = q0 + 16 * w + 4 * kg + r;
            AO[((size_t)(b * 2048 + q)) * 768 + h * 64 + vt * 16 + col] =
                f2b(o_acc[vt][r] * linv[r]);
        }
}

extern "C" void kernel_launch(void* const* d_in, const int* in_sizes, int n_in,
                              void* d_out, int out_size, void* d_ws, size_t ws_size,
                              hipStream_t stream) {
    const float* hs = (const float*)d_in[0];
    const float* wq = (const float*)d_in[1];
    const float* bq = (const float*)d_in[2];
    const float* wk = (const float*)d_in[3];
    const float* bk = (const float*)d_in[4];
    const float* wv = (const float*)d_in[5];
    const float* bv = (const float*)d_in[6];
    const float* wo = (const float*)d_in[7];
    const float* bo = (const float*)d_in[8];
    float* out = (float*)d_out;

    const size_t NB = (size_t)8192 * 768;     // elements per [B*L, DM] tensor
    ushort_t* Qb = (ushort_t*)d_ws;
    ushort_t* Kb = Qb + NB;
    ushort_t* Vb = Kb + NB;
    ushort_t* AO = Vb + NB;

    dim3 blk(256);
    gemm_tn<0><<<dim3(128, 12), blk, 0, stream>>>(hs, wq, bq, Qb);
    gemm_tn<0><<<dim3(128, 12), blk, 0, stream>>>(hs, wk, bk, Kb);
    gemm_tn<0><<<dim3(128, 12), blk, 0, stream>>>(hs, wv, bv, Vb);
    attn_mfma<<<dim3(32, 48), blk, 0, stream>>>(Qb, Kb, Vb, AO);
    gemm_tn<1><<<dim3(128, 12), blk, 0, stream>>>(AO, wo, bo, out);
}

// Round 4
// 524.381 us; speedup vs baseline: 5.3225x; 1.9739x over previous
//
#include <hip/hip_runtime.h>

typedef unsigned short ushort_t;
typedef __attribute__((ext_vector_type(8))) short short8;
typedef __attribute__((ext_vector_type(4))) float f32x4;

__device__ __forceinline__ ushort_t f2b(float f) {
    union { float f; unsigned int i; } v; v.f = f;
    unsigned int x = v.i;
    unsigned int r = (x + 0x7fffu + ((x >> 16) & 1u)) >> 16;
    return (ushort_t)r;
}

// ---------------- fp32 -> bf16 conversion pre-pass ------------------------
__global__ __launch_bounds__(256)
void convert_bf16(const float* __restrict__ hs, const float* __restrict__ wq,
                  const float* __restrict__ wk, const float* __restrict__ wv,
                  const float* __restrict__ wo,
                  ushort_t* __restrict__ hsb, ushort_t* __restrict__ wqb,
                  ushort_t* __restrict__ wkb, ushort_t* __restrict__ wvb,
                  ushort_t* __restrict__ wob)
{
    const int y = blockIdx.y;
    const float* src; ushort_t* dst; int n;
    if (y == 0)      { src = hs; dst = hsb; n = 8192 * 768; }
    else if (y == 1) { src = wq; dst = wqb; n = 768 * 768; }
    else if (y == 2) { src = wk; dst = wkb; n = 768 * 768; }
    else if (y == 3) { src = wv; dst = wvb; n = 768 * 768; }
    else             { src = wo; dst = wob; n = 768 * 768; }
    const int idx = (blockIdx.x * 256 + threadIdx.x) * 8;
    if (idx >= n) return;
    const float4 a = ((const float4*)(src + idx))[0];
    const float4 b = ((const float4*)(src + idx))[1];
    ushort_t tmp[8] = { f2b(a.x), f2b(a.y), f2b(a.z), f2b(a.w),
                        f2b(b.x), f2b(b.y), f2b(b.z), f2b(b.w) };
    *(uint4*)(dst + idx) = *(const uint4*)tmp;
}

// ---------------- MFMA GEMM: C[m,o] = sum_k A[m,k] * W[o,k] + bias[o] -----
// A: bf16 [8192][768] row-major. W: bf16 [768][768] row-major. bias fp32.
// Block 256 thr = 4 waves; block tile 128(m) x 64(o); wave tile 64x32.
// Fragments streamed straight from global (k-contiguous short8, coalesced).
// MODE 0: C = bf16 stored to [B=4][H=12][L=2048][HD=64]; blockIdx.z selects
//         one of 3 weight/bias/dst sets (fused QKV).
// MODE 1: C = fp32 row-major [m][o].
template<int MODE>
__global__ __launch_bounds__(256, 3)
void gemm_mfma(const ushort_t* __restrict__ A,
               const ushort_t* __restrict__ W0, const ushort_t* __restrict__ W1,
               const ushort_t* __restrict__ W2,
               const float* __restrict__ b0, const float* __restrict__ b1,
               const float* __restrict__ b2,
               void* __restrict__ C0, void* __restrict__ C1, void* __restrict__ C2)
{
    const int z = blockIdx.z;
    const ushort_t* W = (z == 0) ? W0 : (z == 1) ? W1 : W2;
    const float* bias  = (z == 0) ? b0 : (z == 1) ? b1 : b2;
    void* C            = (z == 0) ? C0 : (z == 1) ? C1 : C2;

    const int lane = threadIdx.x & 63;
    const int w    = threadIdx.x >> 6;
    const int col  = lane & 15;          // m (A-frag) / o (B-frag) / C col
    const int kg   = lane >> 4;          // k-group
    const int m_base = blockIdx.x * 128 + (w & 1) * 64;
    const int o_base = blockIdx.y * 64 + (w >> 1) * 32;

    const ushort_t* pa = A + (size_t)(m_base + col) * 768 + kg * 8;
    const ushort_t* pw = W + (size_t)(o_base + col) * 768 + kg * 8;

    f32x4 acc[4][2];
#pragma unroll
    for (int mt = 0; mt < 4; ++mt)
#pragma unroll
        for (int nt = 0; nt < 2; ++nt) acc[mt][nt] = (f32x4){0.f, 0.f, 0.f, 0.f};

    short8 af[2][4][2], bf[2][2][2];
#pragma unroll
    for (int mt = 0; mt < 4; ++mt) {
        af[0][mt][0] = *(const short8*)(pa + mt * 16 * 768);
        af[0][mt][1] = *(const short8*)(pa + mt * 16 * 768 + 32);
    }
#pragma unroll
    for (int nt = 0; nt < 2; ++nt) {
        bf[0][nt][0] = *(const short8*)(pw + nt * 16 * 768);
        bf[0][nt][1] = *(const short8*)(pw + nt * 16 * 768 + 32);
    }

#pragma unroll
    for (int it = 0; it < 12; ++it) {
        const int cur = it & 1, nxt = cur ^ 1;
        if (it < 11) {
            const int kn = (it + 1) * 64;
#pragma unroll
            for (int mt = 0; mt < 4; ++mt) {
                af[nxt][mt][0] = *(const short8*)(pa + mt * 16 * 768 + kn);
                af[nxt][mt][1] = *(const short8*)(pa + mt * 16 * 768 + kn + 32);
            }
#pragma unroll
            for (int nt = 0; nt < 2; ++nt) {
                bf[nxt][nt][0] = *(const short8*)(pw + nt * 16 * 768 + kn);
                bf[nxt][nt][1] = *(const short8*)(pw + nt * 16 * 768 + kn + 32);
            }
        }
#pragma unroll
        for (int mt = 0; mt < 4; ++mt)
#pragma unroll
            for (int nt = 0; nt < 2; ++nt) {
                acc[mt][nt] = __builtin_amdgcn_mfma_f32_16x16x32_bf16(
                    af[cur][mt][0], bf[cur][nt][0], acc[mt][nt], 0, 0, 0);
                acc[mt][nt] = __builtin_amdgcn_mfma_f32_16x16x32_bf16(
                    af[cur][mt][1], bf[cur][nt][1], acc[mt][nt], 0, 0, 0);
            }
    }

    float bias_v[2];
#pragma unroll
    for (int nt = 0; nt < 2; ++nt) bias_v[nt] = bias[o_base + nt * 16 + col];

#pragma unroll
    for (int mt = 0; mt < 4; ++mt)
#pragma unroll
        for (int nt = 0; nt < 2; ++nt)
#pragma unroll
            for (int r = 0; r < 4; ++r) {
                const int m = m_base + mt * 16 + kg * 4 + r;
                const int o = o_base + nt * 16 + col;
                const float v = acc[mt][nt][r] + bias_v[nt];
                if (MODE == 0) {
                    const size_t dst = ((size_t)((m >> 11) * 12 + (o >> 6)) << 17)
                                     + ((size_t)(m & 2047) << 6) + (o & 63);
                    ((ushort_t*)C)[dst] = f2b(v);
                } else {
                    ((float*)C)[(size_t)m * 768 + o] = v;
                }
            }
}

// ---------------- MFMA flash attention (unchanged, round-3 verified) ------
#define VT_STRIDE 72

__global__ __launch_bounds__(256)
void attn_mfma(const ushort_t* __restrict__ Q, const ushort_t* __restrict__ K,
               const ushort_t* __restrict__ V, ushort_t* __restrict__ AO)
{
    __shared__ ushort_t Vt[64 * VT_STRIDE];
    __shared__ ushort_t Ps[4][16 * VT_STRIDE];

    const int t    = threadIdx.x;
    const int lane = t & 63;
    const int w    = t >> 6;
    const int bh   = blockIdx.y;
    const int qt   = 31 - (int)blockIdx.x;
    const int q0   = qt << 6;
    const size_t base = (size_t)bh << 17;

    const int col = lane & 15;
    const int kg  = lane >> 4;

    short8 aq0, aq1;
    {
        const ushort_t* pq = Q + base + (size_t)(q0 + 16 * w + col) * 64 + kg * 8;
        aq0 = *(const short8*)(pq);
        aq1 = *(const short8*)(pq + 32);
    }

    float m_st[4], l_st[4];
#pragma unroll
    for (int r = 0; r < 4; ++r) { m_st[r] = -3.0e38f; l_st[r] = 0.f; }
    f32x4 o_acc[4];
#pragma unroll
    for (int vt = 0; vt < 4; ++vt) o_acc[vt] = (f32x4){0.f, 0.f, 0.f, 0.f};

    const int vkey = lane, vdg = w;

    for (int c = 0; c <= qt; ++c) {
        const int k0 = c << 6;

        short8 bk[4][2];
#pragma unroll
        for (int kt = 0; kt < 4; ++kt) {
            const ushort_t* pk = K + base + (size_t)(k0 + kt * 16 + col) * 64 + kg * 8;
            bk[kt][0] = *(const short8*)(pk);
            bk[kt][1] = *(const short8*)(pk + 32);
        }
        const ushort_t* pv = V + base + (size_t)(k0 + vkey) * 64 + vdg * 16;
        const uint4 v0 = *(const uint4*)pv;
        const uint4 v1 = *(const uint4*)(pv + 8);

        __syncthreads();
        {
            ushort_t tmp[16];
            *(uint4*)tmp = v0; *(uint4*)(tmp + 8) = v1;
#pragma unroll
            for (int i = 0; i < 16; ++i)
                Vt[(vdg * 16 + i) * VT_STRIDE + vkey] = tmp[i];
        }
        __syncthreads();

        f32x4 s[4];
#pragma unroll
        for (int kt = 0; kt < 4; ++kt) {
            f32x4 acc = (f32x4){0.f, 0.f, 0.f, 0.f};
            acc = __builtin_amdgcn_mfma_f32_16x16x32_bf16(aq0, bk[kt][0], acc, 0, 0, 0);
            acc = __builtin_amdgcn_mfma_f32_16x16x32_bf16(aq1, bk[kt][1], acc, 0, 0, 0);
            s[kt] = acc;
        }
        const int qrow_base = q0 + 16 * w + 4 * kg;
        if (c == qt) {
#pragma unroll
            for (int kt = 0; kt < 4; ++kt)
#pragma unroll
                for (int r = 0; r < 4; ++r) {
                    const int key = k0 + kt * 16 + col;
                    s[kt][r] = (key > qrow_base + r) ? -3.0e38f : s[kt][r] * 0.125f;
                }
        } else {
#pragma unroll
            for (int kt = 0; kt < 4; ++kt)
#pragma unroll
                for (int r = 0; r < 4; ++r) s[kt][r] *= 0.125f;
        }

        float alpha[4];
#pragma unroll
        for (int r = 0; r < 4; ++r) {
            float mx = fmaxf(fmaxf(s[0][r], s[1][r]), fmaxf(s[2][r], s[3][r]));
            mx = fmaxf(mx, __shfl_xor(mx, 1));
            mx = fmaxf(mx, __shfl_xor(mx, 2));
            mx = fmaxf(mx, __shfl_xor(mx, 4));
            mx = fmaxf(mx, __shfl_xor(mx, 8));
            const float mn = fmaxf(m_st[r], mx);
            alpha[r] = __expf(m_st[r] - mn);
            m_st[r] = mn;
            float ls = 0.f;
#pragma unroll
            for (int kt = 0; kt < 4; ++kt) {
                const float p = __expf(s[kt][r] - mn);
                s[kt][r] = p;
                ls += p;
            }
            ls += __shfl_xor(ls, 1);
            ls += __shfl_xor(ls, 2);
            ls += __shfl_xor(ls, 4);
            ls += __shfl_xor(ls, 8);
            l_st[r] = l_st[r] * alpha[r] + ls;
        }

        ushort_t* ps = Ps[w];
#pragma unroll
        for (int kt = 0; kt < 4; ++kt)
#pragma unroll
            for (int r = 0; r < 4; ++r)
                ps[(4 * kg + r) * VT_STRIDE + kt * 16 + col] = f2b(s[kt][r]);
        short8 pa0, pa1;
        {
            const ushort_t* pp = ps + (size_t)col * VT_STRIDE + kg * 8;
            pa0 = *(const short8*)pp;
            pa1 = *(const short8*)(pp + 32);
        }

#pragma unroll
        for (int vt = 0; vt < 4; ++vt) {
            f32x4 o = o_acc[vt];
#pragma unroll
            for (int r = 0; r < 4; ++r) o[r] *= alpha[r];
            const ushort_t* pvt = Vt + (vt * 16 + col) * VT_STRIDE + kg * 8;
            const short8 bv0 = *(const short8*)pvt;
            const short8 bv1 = *(const short8*)(pvt + 32);
            o = __builtin_amdgcn_mfma_f32_16x16x32_bf16(pa0, bv0, o, 0, 0, 0);
            o = __builtin_amdgcn_mfma_f32_16x16x32_bf16(pa1, bv1, o, 0, 0, 0);
            o_acc[vt] = o;
        }
    }

    float linv[4];
#pragma unroll
    for (int r = 0; r < 4; ++r) linv[r] = 1.f / l_st[r];
    const int b = bh / 12, h = bh % 12;
#pragma unroll
    for (int vt = 0; vt < 4; ++vt)
#pragma unroll
        for (int r = 0; r < 4; ++r) {
            const int q = q0 + 16 * w + 4 * kg + r;
            AO[((size_t)(b * 2048 + q)) * 768 + h * 64 + vt * 16 + col] =
                f2b(o_acc[vt][r] * linv[r]);
        }
}

extern "C" void kernel_launch(void* const* d_in, const int* in_sizes, int n_in,
                              void* d_out, int out_size, void* d_ws, size_t ws_size,
                              hipStream_t stream) {
    const float* hs = (const float*)d_in[0];
    const float* wq = (const float*)d_in[1];
    const float* bq = (const float*)d_in[2];
    const float* wk = (const float*)d_in[3];
    const float* bk = (const float*)d_in[4];
    const float* wv = (const float*)d_in[5];
    const float* bv = (const float*)d_in[6];
    const float* wo = (const float*)d_in[7];
    const float* bo = (const float*)d_in[8];
    float* out = (float*)d_out;

    const size_t NB = (size_t)8192 * 768;   // [B*L, DM] elements
    const size_t WN = (size_t)768 * 768;    // weight elements
    ushort_t* hsb = (ushort_t*)d_ws;        // aliased: becomes AO after QKV GEMMs
    ushort_t* Qb  = hsb + NB;
    ushort_t* Kb  = Qb + NB;
    ushort_t* Vb  = Kb + NB;
    ushort_t* wqb = Vb + NB;
    ushort_t* wkb = wqb + WN;
    ushort_t* wvb = wkb + WN;
    ushort_t* wob = wvb + WN;
    ushort_t* AO  = hsb;                    // hs_bf16 is dead once attn runs

    dim3 blk(256);
    convert_bf16<<<dim3(3072, 5), blk, 0, stream>>>(hs, wq, wk, wv, wo,
                                                    hsb, wqb, wkb, wvb, wob);
    gemm_mfma<0><<<dim3(64, 12, 3), blk, 0, stream>>>(hsb, wqb, wkb, wvb,
                                                      bq, bk, bv, Qb, Kb, Vb);
    attn_mfma<<<dim3(32, 48), blk, 0, stream>>>(Qb, Kb, Vb, AO);
    gemm_mfma<1><<<dim3(64, 12, 1), blk, 0, stream>>>(AO, wob, wob, wob,
                                                      bo, bo, bo, out, out, out);
}